// Round 16
// baseline (1595.551 us; speedup 1.0000x reference)
//
#include <hip/hip_runtime.h>
#include <hip/hip_fp8.h>
#include <cstdint>
#include <cstddef>

typedef _Float16 f16;
typedef _Float16 f16x8 __attribute__((ext_vector_type(8)));
typedef float f32x4 __attribute__((ext_vector_type(4)));
typedef unsigned char u8;
typedef unsigned long long u64;

#define MFMA16(a,b,c) __builtin_amdgcn_mfma_f32_16x16x32_f16((a),(b),(c),0,0,0)
#define MFMA8(a,b,c)  __builtin_amdgcn_mfma_f32_16x16x32_fp8_fp8((long)(a),(long)(b),(c),0,0,0)

constexpr int Bb = 64, Tt = 48, Ee = 620, Hh = 2400;
constexpr int G3 = 3*Hh;        // 7200
constexpr int EPAD = 640;
constexpr int JT = Hh/16;       // 150
constexpr int KK_HH = Hh/32;    // 75
constexpr int KK_IH = EPAD/32;  // 20
constexpr int NT_ALL = G3/16;   // 450
constexpr int KSTG = 50;        // kk staged in LDS (0..49); 50..74 from global

constexpr size_t WHH_ELEMS = (size_t)NT_ALL*KK_HH*64*8;  // 17,280,000
constexpr size_t WIH_ELEMS = (size_t)NT_ALL*KK_IH*64*8;  // 4,608,000
constexpr size_t X_ELEMS   = (size_t)Bb*Tt*EPAD;         // xpack: [192 mt][20 kk][64][8]
constexpr size_t GI_ELEMS  = (size_t)Bb*Tt*G3;           // gi2: [450][3072][16]
constexpr size_t HB        = (size_t)Bb*Hh;              // h packs: [4 mt][75 kk][64][8]

constexpr float F16_MIN_NORMAL = 6.103515625e-05f;
constexpr float LO_SCALE = 8388608.0f;   // 2^23
constexpr float LO_INV   = 1.0f/8388608.0f;

__device__ __forceinline__ float sigf(float x){ return 1.0f/(1.0f+expf(-x)); }
__device__ __forceinline__ u8 to_fp8(float x){
    __hip_fp8_e4m3 v(x); return *(u8*)&v;
}

// ---- pack w_hh: hi f16 frags + lo fp8 (residual x 2^23) ----
__global__ __launch_bounds__(256) void k_pack_whh(const float* __restrict__ w,
                                                  f16* __restrict__ hi,
                                                  u8* __restrict__ lo8){
    size_t idx = (size_t)blockIdx.x*256 + threadIdx.x;
    if (idx >= WHH_ELEMS) return;
    int j = (int)(idx & 7);
    int l = (int)((idx >> 3) & 63);
    size_t rem = idx >> 9;
    int kk = (int)(rem % KK_HH);
    int nt = (int)(rem / KK_HH);
    int row = nt*16 + (l & 15);
    int k   = kk*32 + ((l >> 4) << 3) + j;
    float v = w[(size_t)row*Hh + k];
    f16 h = (fabsf(v) >= F16_MIN_NORMAL) ? (f16)v : (f16)0.0f;
    hi[idx]  = h;
    lo8[idx] = to_fp8((v - (float)h) * LO_SCALE);
}

__global__ __launch_bounds__(256) void k_pack_wih(const float* __restrict__ w, f16* __restrict__ p){
    size_t idx = (size_t)blockIdx.x*256 + threadIdx.x;
    if (idx >= WIH_ELEMS) return;
    int j = (int)(idx & 7);
    int l = (int)((idx >> 3) & 63);
    size_t rem = idx >> 9;
    int kk = (int)(rem % KK_IH);
    int nt = (int)(rem / KK_IH);
    int row = nt*16 + (l & 15);
    int k   = kk*32 + ((l >> 4) << 3) + j;
    float v = (k < Ee) ? w[(size_t)row*Ee + k] : 0.0f;
    p[idx] = (f16)v;
}

// ---- gather embeddings directly into A-fragment layout ----
__global__ __launch_bounds__(256) void k_gather_x(const int* __restrict__ tokens,
                                                  const float* __restrict__ emb,
                                                  f16* __restrict__ xp){
    size_t idx = (size_t)blockIdx.x*256 + threadIdx.x;
    if (idx >= X_ELEMS) return;
    int row = (int)(idx / EPAD);
    int e   = (int)(idx % EPAD);
    int tok = tokens[row];
    float v = (e < Ee) ? emb[(size_t)tok*Ee + e] : 0.0f;
    size_t fo = ((size_t)(row >> 4)*KK_IH + (e >> 5))*512
              + (size_t)((((e & 31) >> 3) << 4) + (row & 15))*8 + (e & 7);
    xp[fo] = (f16)v;
}

// ---- gi = x(frag) @ w_ih^T: R14 version (plain stores), 2 m-tiles/wave ----
__global__ __launch_bounds__(512) void k_gi_gemm(const f16* __restrict__ xp,
                                                 const f16* __restrict__ wp,
                                                 f16* __restrict__ gi2){
    __shared__ char smem[61440];
    const int tid = threadIdx.x;
    const int wv = tid >> 6;
    const int l  = tid & 63;
    const int mt0 = blockIdx.x*16 + wv*2;
    const int nt0 = blockIdx.y*3;

    {
        const char* base = (const char*)wp;
        for (int off = tid*16; off < 61440; off += 8192){
            int g = off / 20480, rem = off - g*20480;
            const char* src = base + (size_t)(nt0+g)*20480 + rem;
            *(float4*)(smem + off) = *(const float4*)src;
        }
    }
    __syncthreads();

    f32x4 z4 = {0.f,0.f,0.f,0.f};
    f32x4 acc[2][3] = {{z4,z4,z4},{z4,z4,z4}};

    const f16x8* pa0 = (const f16x8*)(xp + ((size_t)mt0*KK_IH*64 + l)*8);
    const f16x8* pa1 = (const f16x8*)(xp + ((size_t)(mt0+1)*KK_IH*64 + l)*8);
    const unsigned lbase = (unsigned)l*16u;

    f16x8 ca0 = pa0[0], ca1 = pa1[0];
    #pragma unroll
    for (int kk=0; kk<KK_IH; ++kk){
        f16x8 na0, na1;
        if (kk+1 < KK_IH){ na0 = pa0[(size_t)(kk+1)*64]; na1 = pa1[(size_t)(kk+1)*64]; }
        f16x8 b0 = *(const f16x8*)(smem +      0u + (unsigned)kk*1024u + lbase);
        f16x8 b1 = *(const f16x8*)(smem + 20480u + (unsigned)kk*1024u + lbase);
        f16x8 b2 = *(const f16x8*)(smem + 40960u + (unsigned)kk*1024u + lbase);
        acc[0][0] = MFMA16(ca0, b0, acc[0][0]);
        acc[1][0] = MFMA16(ca1, b0, acc[1][0]);
        acc[0][1] = MFMA16(ca0, b1, acc[0][1]);
        acc[1][1] = MFMA16(ca1, b1, acc[1][1]);
        acc[0][2] = MFMA16(ca0, b2, acc[0][2]);
        acc[1][2] = MFMA16(ca1, b2, acc[1][2]);
        if (kk+1 < KK_IH){ ca0 = na0; ca1 = na1; }
    }

    __syncthreads();
    {
        const int rb = (l >> 4)*4;
        const int jc = l & 15;
        #pragma unroll
        for (int mt=0; mt<2; ++mt){
            #pragma unroll
            for (int r=0; r<4; ++r){
                int ml = (wv*2 + mt)*16 + rb + r;
                *(f16*)(smem + ((0*256 + ml)*16 + jc)*2) = (f16)acc[mt][0][r];
                *(f16*)(smem + ((1*256 + ml)*16 + jc)*2) = (f16)acc[mt][1][r];
                *(f16*)(smem + ((2*256 + ml)*16 + jc)*2) = (f16)acc[mt][2][r];
            }
        }
    }
    __syncthreads();
    for (int u = tid; u < 1536; u += 512){
        int g  = u / 512;
        int rem = u - g*512;
        int ml = rem >> 1, half = rem & 1;
        size_t dst = ((size_t)(nt0+g)*3072 + (size_t)blockIdx.x*256 + ml)*16 + half*8;
        *(float4*)(&gi2[dst]) = *(const float4*)(smem + (size_t)u*16);
    }
}

// ---- fused GRU step: full-K per jt-block + in-kernel combine epilogue ----
// 150 blocks x 512 thr (4 m-tiles x 2 k-halves); kk 0..49 LDS, 50..74 global
__global__ __launch_bounds__(512) void k_step_fused(
    int t,
    const f16* __restrict__ hhi, const f16* __restrict__ hlo, const u8* __restrict__ hq8,
    f16* __restrict__ nhhi, f16* __restrict__ nhlo, u8* __restrict__ nhq8,
    const f16* __restrict__ whi, const u8* __restrict__ wlo,
    const f16* __restrict__ gi2, const float* __restrict__ bhh,
    const int* __restrict__ lens, float* __restrict__ out)
{
    __shared__ char smem[153600];   // 3 nt x 50 kk x 1KB (aliased as red after barrier)
    const int tid = threadIdx.x;
    const int wv = tid >> 6;        // 0..7
    const int l  = tid & 63;
    const int m  = wv & 3;          // m-tile (16 batch rows)
    const int kh = wv >> 2;         // k-half
    const int jt = blockIdx.x;      // 0..149

    // ---- stage W-hi kk 0..49 for 3 gates ----
    for (int off = tid*16; off < 153600; off += 8192){
        int ntl = off / 51200, rem = off - ntl*51200;    // 50 kk x 1024 per nt
        size_t nt = (size_t)ntl*JT + jt;
        const char* src = (const char*)whi + nt*(size_t)KK_HH*1024 + rem;
        *(float4*)(smem + off) = *(const float4*)src;
    }
    __syncthreads();

    const int kb = kh ? 42 : 0;
    const int keL = kh ? KSTG : 42;     // LDS-segment end

    // A pointers (frag-packed, full-K): index [(kk)*64]
    const f16x8* pah = (const f16x8*)(hhi + ((size_t)m*KK_HH*64 + l)*8);
    const f16x8* pal = (const f16x8*)(hlo + ((size_t)m*KK_HH*64 + l)*8);
    const u64*   paq = (const u64*)(hq8 + ((size_t)m*KK_HH*64 + l)*8);
    // W-lo (fp8) global pointers per gate: index [(kk)*64] on u64*
    const u64* pbl0 = (const u64*)(wlo + ((size_t)(0*JT+jt)*KK_HH)*512 + (size_t)l*8);
    const u64* pbl1 = (const u64*)(wlo + ((size_t)(1*JT+jt)*KK_HH)*512 + (size_t)l*8);
    const u64* pbl2 = (const u64*)(wlo + ((size_t)(2*JT+jt)*KK_HH)*512 + (size_t)l*8);
    // W-hi global pointers (for kk >= KSTG): index [(kk)*64] on f16x8*
    const f16x8* pbg0 = (const f16x8*)(whi + ((size_t)(0*JT+jt)*KK_HH*64 + l)*8);
    const f16x8* pbg1 = (const f16x8*)(whi + ((size_t)(1*JT+jt)*KK_HH*64 + l)*8);
    const f16x8* pbg2 = (const f16x8*)(whi + ((size_t)(2*JT+jt)*KK_HH*64 + l)*8);

    f32x4 z4 = {0.f,0.f,0.f,0.f};
    f32x4 ah0=z4, ah1=z4, ah2=z4;
    f32x4 al0=z4, al1=z4, al2=z4;

    // ---- segment 1: B-hi from LDS, kk in [kb, keL) ----
    {
        f16x8 cah = pah[(size_t)kb*64];
        f16x8 cal = pal[(size_t)kb*64];
        u64   caq = paq[(size_t)kb*64];
        u64 cl0 = pbl0[(size_t)kb*64];
        u64 cl1 = pbl1[(size_t)kb*64];
        u64 cl2 = pbl2[(size_t)kb*64];
        for (int kk=kb; kk<keL; ++kk){
            f16x8 nah, nal; u64 naq, nl0, nl1, nl2;
            if (kk+1 < keL){
                nah = pah[(size_t)(kk+1)*64];
                nal = pal[(size_t)(kk+1)*64];
                naq = paq[(size_t)(kk+1)*64];
                nl0 = pbl0[(size_t)(kk+1)*64];
                nl1 = pbl1[(size_t)(kk+1)*64];
                nl2 = pbl2[(size_t)(kk+1)*64];
            }
            const unsigned ko = (unsigned)kk*1024u + (unsigned)l*16u;
            f16x8 b0 = *(const f16x8*)(smem +      0u + ko);
            f16x8 b1 = *(const f16x8*)(smem +  51200u + ko);
            f16x8 b2 = *(const f16x8*)(smem + 102400u + ko);
            ah0 = MFMA16(cah, b0, ah0);
            al0 = MFMA16(cal, b0, al0);
            al0 = MFMA8(caq, cl0, al0);
            ah1 = MFMA16(cah, b1, ah1);
            al1 = MFMA16(cal, b1, al1);
            al1 = MFMA8(caq, cl1, al1);
            ah2 = MFMA16(cah, b2, ah2);
            al2 = MFMA16(cal, b2, al2);
            al2 = MFMA8(caq, cl2, al2);
            if (kk+1 < keL){
                cah=nah; cal=nal; caq=naq;
                cl0=nl0; cl1=nl1; cl2=nl2;
            }
        }
    }
    // ---- segment 2 (kh==1 only): B-hi from global, kk in [KSTG, 75) ----
    if (kh == 1){
        f16x8 cah = pah[(size_t)KSTG*64];
        f16x8 cal = pal[(size_t)KSTG*64];
        u64   caq = paq[(size_t)KSTG*64];
        f16x8 cb0 = pbg0[(size_t)KSTG*64];
        f16x8 cb1 = pbg1[(size_t)KSTG*64];
        f16x8 cb2 = pbg2[(size_t)KSTG*64];
        u64 cl0 = pbl0[(size_t)KSTG*64];
        u64 cl1 = pbl1[(size_t)KSTG*64];
        u64 cl2 = pbl2[(size_t)KSTG*64];
        for (int kk=KSTG; kk<KK_HH; ++kk){
            f16x8 nah, nal, nb0, nb1, nb2; u64 naq, nl0, nl1, nl2;
            if (kk+1 < KK_HH){
                nah = pah[(size_t)(kk+1)*64];
                nal = pal[(size_t)(kk+1)*64];
                naq = paq[(size_t)(kk+1)*64];
                nb0 = pbg0[(size_t)(kk+1)*64];
                nb1 = pbg1[(size_t)(kk+1)*64];
                nb2 = pbg2[(size_t)(kk+1)*64];
                nl0 = pbl0[(size_t)(kk+1)*64];
                nl1 = pbl1[(size_t)(kk+1)*64];
                nl2 = pbl2[(size_t)(kk+1)*64];
            }
            ah0 = MFMA16(cah, cb0, ah0);
            al0 = MFMA16(cal, cb0, al0);
            al0 = MFMA8(caq, cl0, al0);
            ah1 = MFMA16(cah, cb1, ah1);
            al1 = MFMA16(cal, cb1, al1);
            al1 = MFMA8(caq, cl1, al1);
            ah2 = MFMA16(cah, cb2, ah2);
            al2 = MFMA16(cal, cb2, al2);
            al2 = MFMA8(caq, cl2, al2);
            if (kk+1 < KK_HH){
                cah=nah; cal=nal; caq=naq;
                cb0=nb0; cb1=nb1; cb2=nb2;
                cl0=nl0; cl1=nl1; cl2=nl2;
            }
        }
    }

    // ---- cross-kh reduce (alias red over stage after all LDS B-reads done) ----
    __syncthreads();
    f32x4* red = (f32x4*)smem;
    if (kh == 1){
        red[(m*3+0)*64 + l] = ah0 + al0*LO_INV;
        red[(m*3+1)*64 + l] = ah1 + al1*LO_INV;
        red[(m*3+2)*64 + l] = ah2 + al2*LO_INV;
    }
    __syncthreads();
    if (kh == 0){
        f32x4 v0 = ah0 + al0*LO_INV + red[(m*3+0)*64 + l];
        f32x4 v1 = ah1 + al1*LO_INV + red[(m*3+1)*64 + l];
        f32x4 v2 = ah2 + al2*LO_INV + red[(m*3+2)*64 + l];

        const int jc = l & 15;
        const int j  = jt*16 + jc;
        const float br = bhh[j], bz = bhh[Hh + j], bn = bhh[2*Hh + j];
        const size_t fbase = ((size_t)(m*KK_HH + (jt >> 1))*64
                           + (size_t)(((jt & 1)*2 + (jc >> 3)) << 4) + (size_t)(l >> 4)*4)*8
                           + (size_t)(l & 7);
        const int b0r = m*16 + (l >> 4)*4;
        #pragma unroll
        for (int r=0; r<4; ++r){
            const int b = b0r + r;
            const size_t row = (size_t)b*Tt + t;
            float gir = (float)gi2[((size_t)(0*JT + jt)*3072 + row)*16 + jc];
            float giz = (float)gi2[((size_t)(1*JT + jt)*3072 + row)*16 + jc];
            float gin = (float)gi2[((size_t)(2*JT + jt)*3072 + row)*16 + jc];
            float rg = sigf(gir + v0[r] + br);
            float zg = sigf(giz + v1[r] + bz);
            float ng = tanhf(gin + rg*(v2[r] + bn));
            const size_t fo = fbase + (size_t)r*8;
            float hp = (float)hhi[fo] + (float)hlo[fo]*LO_INV;
            float hn = (1.0f - zg)*ng + zg*hp;
            f16 h16 = (fabsf(hn) >= F16_MIN_NORMAL) ? (f16)hn : (f16)0.0f;
            nhhi[fo] = h16;
            nhlo[fo] = (f16)((hn - (float)h16)*LO_SCALE);
            nhq8[fo] = to_fp8(hn);
            if (lens[b] - 1 == t) out[(size_t)b*Hh + j] = hn;
        }
    }
}

// ---- fallback (small ws): plain fp32 ----
__global__ __launch_bounds__(256) void k_fb_step(
    int t, const float* __restrict__ hcur, float* __restrict__ hnext,
    const int* __restrict__ tokens, const int* __restrict__ lens,
    const float* __restrict__ emb, const float* __restrict__ wih,
    const float* __restrict__ whh, const float* __restrict__ bhh,
    float* __restrict__ out)
{
    __shared__ float sbuf[64][17];
    __shared__ int stok[64];
    const int tid = threadIdx.x;
    const int jl = tid & 7, rl = tid >> 3;
    const int j = blockIdx.x*8 + jl;
    if (tid < 64) stok[tid] = tokens[tid*Tt + t];

    float accr[2]={0.f,0.f}, accz[2]={0.f,0.f}, accnh[2]={0.f,0.f}, accni[2]={0.f,0.f};

    for (int k0=0; k0<Hh; k0+=16){
        __syncthreads();
        for (int e=tid; e<1024; e+=256)
            sbuf[e>>4][e&15] = hcur[(size_t)(e>>4)*Hh + k0 + (e&15)];
        __syncthreads();
        for (int kk=0; kk<16; ++kk){
            int k = k0 + kk;
            float wr = whh[(size_t)j*Hh + k];
            float wz = whh[(size_t)(Hh + j)*Hh + k];
            float wn = whh[(size_t)(2*Hh + j)*Hh + k];
            #pragma unroll
            for (int rr=0; rr<2; ++rr){
                float hv = sbuf[rl*2 + rr][kk];
                accr[rr] += wr*hv; accz[rr] += wz*hv; accnh[rr] += wn*hv;
            }
        }
    }
    for (int k0=0; k0<Ee; k0+=16){
        int lim = (Ee - k0 < 16) ? (Ee - k0) : 16;
        __syncthreads();
        for (int e=tid; e<1024; e+=256){
            int rr = e>>4, kkk = e&15;
            sbuf[rr][kkk] = (kkk < lim) ? emb[(size_t)stok[rr]*Ee + k0 + kkk] : 0.0f;
        }
        __syncthreads();
        for (int kk=0; kk<lim; ++kk){
            int k = k0 + kk;
            float wr = wih[(size_t)j*Ee + k];
            float wz = wih[(size_t)(Hh + j)*Ee + k];
            float wn = wih[(size_t)(2*Hh + j)*Ee + k];
            #pragma unroll
            for (int rr=0; rr<2; ++rr){
                float hv = sbuf[rl*2 + rr][kk];
                accr[rr] += wr*hv; accz[rr] += wz*hv; accni[rr] += wn*hv;
            }
        }
    }
    const float br = bhh[j], bz = bhh[Hh + j], bn = bhh[2*Hh + j];
    #pragma unroll
    for (int rr=0; rr<2; ++rr){
        int b = rl*2 + rr;
        float rg = sigf(accr[rr] + br);
        float zg = sigf(accz[rr] + bz);
        float ng = tanhf(accni[rr] + rg*(accnh[rr] + bn));
        float hp = hcur[(size_t)b*Hh + j];
        float hn = (1.0f - zg)*ng + zg*hp;
        hnext[(size_t)b*Hh + j] = hn;
        if (lens[b] - 1 == t) out[(size_t)b*Hh + j] = hn;
    }
}

static inline size_t alignup(size_t v){ return (v + 255) & ~(size_t)255; }

extern "C" void kernel_launch(void* const* d_in, const int* in_sizes, int n_in,
                              void* d_out, int out_size, void* d_ws, size_t ws_size,
                              hipStream_t stream)
{
    const int*   tokens = (const int*)d_in[0];
    const int*   lens   = (const int*)d_in[1];
    const float* emb    = (const float*)d_in[2];
    const float* wih    = (const float*)d_in[3];
    const float* whh    = (const float*)d_in[4];
    const float* bhh    = (const float*)d_in[5];
    float* out = (float*)d_out;

    char* ws = (char*)d_ws;
    size_t o = 0;
    const size_t o_whi  = o; o = alignup(o + WHH_ELEMS*2);
    const size_t o_wlo8 = o; o = alignup(o + WHH_ELEMS);
    const size_t o_wih  = o; o = alignup(o + WIH_ELEMS*2);
    const size_t o_x    = o; o = alignup(o + X_ELEMS*2);
    const size_t o_gi   = o; o = alignup(o + GI_ELEMS*2);
    const size_t hbytes = HB*2 + HB*2 + HB;   // hi, lo, q8
    const size_t o_hbuf = o; o = alignup(o + 2*hbytes);
    const size_t need = o;   // ~111 MB

    if (ws_size >= need) {
        f16* whip = (f16*)(ws + o_whi);
        u8*  wlop = (u8*)(ws + o_wlo8);
        f16* wihp = (f16*)(ws + o_wih);
        f16* xp   = (f16*)(ws + o_x);
        f16* gip  = (f16*)(ws + o_gi);
        char* hb = ws + o_hbuf;
        f16* hhi[2]; f16* hlo[2]; u8* hq8[2];
        for (int i=0; i<2; ++i){
            char* p = hb + i*hbytes;
            hhi[i] = (f16*)p;
            hlo[i] = (f16*)(p + HB*2);
            hq8[i] = (u8*)(p + HB*4);
        }

        hipMemsetAsync(hb, 0, 2*hbytes, stream);
        k_pack_whh<<<dim3((unsigned)((WHH_ELEMS+255)/256)), dim3(256), 0, stream>>>(whh, whip, wlop);
        k_pack_wih<<<dim3((unsigned)((WIH_ELEMS+255)/256)), dim3(256), 0, stream>>>(wih, wihp);
        k_gather_x<<<dim3((unsigned)((X_ELEMS+255)/256)),  dim3(256), 0, stream>>>(tokens, emb, xp);
        k_gi_gemm<<<dim3(12,150), dim3(512), 0, stream>>>(xp, wihp, gip);
        for (int t=0; t<Tt; ++t){
            int c = t & 1, n = c ^ 1;
            k_step_fused<<<dim3(JT), dim3(512), 0, stream>>>(t,
                hhi[c], hlo[c], hq8[c],
                hhi[n], hlo[n], hq8[n],
                whip, wlop, gip, bhh, lens, out);
        }
    } else {
        float* h32 = (float*)ws;
        float* hbuf[2] = { h32, h32 + HB };
        hipMemsetAsync(ws, 0, 2*HB*4, stream);
        for (int t=0; t<Tt; ++t){
            int c = t & 1, n = c ^ 1;
            k_fb_step<<<dim3(300), dim3(256), 0, stream>>>(t, hbuf[c], hbuf[n],
                tokens, lens, emb, wih, whh, bhh, out);
        }
    }
}

// Round 17
// 924.142 us; speedup vs baseline: 1.7265x; 1.7265x over previous
//
#include <hip/hip_runtime.h>
#include <cstdint>
#include <cstddef>

typedef _Float16 f16;
typedef _Float16 f16x8 __attribute__((ext_vector_type(8)));
typedef float f32x4 __attribute__((ext_vector_type(4)));
typedef unsigned char u8;
typedef unsigned long long u64;

#define MFMA16(a,b,c) __builtin_amdgcn_mfma_f32_16x16x32_f16((a),(b),(c),0,0,0)

constexpr int Bb = 64, Tt = 48, Ee = 620, Hh = 2400;
constexpr int G3 = 3*Hh;        // 7200
constexpr int EPAD = 640;
constexpr int JT = Hh/16;       // 150
constexpr int KK_HH = Hh/32;    // 75
constexpr int KK_IH = EPAD/32;  // 20
constexpr int NT_ALL = G3/16;   // 450
constexpr int KS = 5;           // K-split for recurrence
constexpr int KKB = KK_HH/KS;   // 15
constexpr int JG = 50;          // jt-groups (3 jt each)

constexpr size_t WHH_ELEMS = (size_t)NT_ALL*KK_HH*64*8;  // 17,280,000
constexpr size_t WIH_ELEMS = (size_t)NT_ALL*KK_IH*64*8;  // 4,608,000
constexpr size_t X_ELEMS   = (size_t)Bb*Tt*EPAD;         // xpack: [192 mt][20 kk][64][8]
constexpr size_t GI_ELEMS  = (size_t)Bb*Tt*G3;           // gi2: [450][3072][16]
constexpr size_t HB        = (size_t)Bb*Hh;              // h pack: [4 mt][75 kk][64][8]

__device__ __forceinline__ float sigf(float x){ return 1.0f/(1.0f+expf(-x)); }

// ---- pack w_hh: f16 frags only ----
// elem (nt,kk,l,j): W[nt*16+(l&15)][kk*32+((l>>4)<<3)+j]
__global__ __launch_bounds__(256) void k_pack_whh(const float* __restrict__ w,
                                                  f16* __restrict__ hi){
    size_t idx = (size_t)blockIdx.x*256 + threadIdx.x;
    if (idx >= WHH_ELEMS) return;
    int j = (int)(idx & 7);
    int l = (int)((idx >> 3) & 63);
    size_t rem = idx >> 9;
    int kk = (int)(rem % KK_HH);
    int nt = (int)(rem / KK_HH);
    int row = nt*16 + (l & 15);
    int k   = kk*32 + ((l >> 4) << 3) + j;
    hi[idx] = (f16)w[(size_t)row*Hh + k];
}

__global__ __launch_bounds__(256) void k_pack_wih(const float* __restrict__ w, f16* __restrict__ p){
    size_t idx = (size_t)blockIdx.x*256 + threadIdx.x;
    if (idx >= WIH_ELEMS) return;
    int j = (int)(idx & 7);
    int l = (int)((idx >> 3) & 63);
    size_t rem = idx >> 9;
    int kk = (int)(rem % KK_IH);
    int nt = (int)(rem / KK_IH);
    int row = nt*16 + (l & 15);
    int k   = kk*32 + ((l >> 4) << 3) + j;
    float v = (k < Ee) ? w[(size_t)row*Ee + k] : 0.0f;
    p[idx] = (f16)v;
}

// ---- gather embeddings directly into A-fragment layout ----
__global__ __launch_bounds__(256) void k_gather_x(const int* __restrict__ tokens,
                                                  const float* __restrict__ emb,
                                                  f16* __restrict__ xp){
    size_t idx = (size_t)blockIdx.x*256 + threadIdx.x;
    if (idx >= X_ELEMS) return;
    int row = (int)(idx / EPAD);
    int e   = (int)(idx % EPAD);
    int tok = tokens[row];
    float v = (e < Ee) ? emb[(size_t)tok*Ee + e] : 0.0f;
    size_t fo = ((size_t)(row >> 4)*KK_IH + (e >> 5))*512
              + (size_t)((((e & 31) >> 3) << 4) + (row & 15))*8 + (e & 7);
    xp[fo] = (f16)v;
}

// ---- gi = x(frag) @ w_ih^T: 2 m-tiles per wave (2 independent A-chains) ----
__global__ __launch_bounds__(512) void k_gi_gemm(const f16* __restrict__ xp,
                                                 const f16* __restrict__ wp,
                                                 f16* __restrict__ gi2){
    __shared__ char smem[61440];
    const int tid = threadIdx.x;
    const int wv = tid >> 6;
    const int l  = tid & 63;
    const int mt0 = blockIdx.x*16 + wv*2;
    const int nt0 = blockIdx.y*3;

    {
        const char* base = (const char*)wp;
        for (int off = tid*16; off < 61440; off += 8192){
            int g = off / 20480, rem = off - g*20480;
            const char* src = base + (size_t)(nt0+g)*20480 + rem;
            *(float4*)(smem + off) = *(const float4*)src;
        }
    }
    __syncthreads();

    f32x4 z4 = {0.f,0.f,0.f,0.f};
    f32x4 acc[2][3] = {{z4,z4,z4},{z4,z4,z4}};

    const f16x8* pa0 = (const f16x8*)(xp + ((size_t)mt0*KK_IH*64 + l)*8);
    const f16x8* pa1 = (const f16x8*)(xp + ((size_t)(mt0+1)*KK_IH*64 + l)*8);
    const unsigned lbase = (unsigned)l*16u;

    f16x8 ca0 = pa0[0], ca1 = pa1[0];
    #pragma unroll
    for (int kk=0; kk<KK_IH; ++kk){
        f16x8 na0, na1;
        if (kk+1 < KK_IH){ na0 = pa0[(size_t)(kk+1)*64]; na1 = pa1[(size_t)(kk+1)*64]; }
        f16x8 b0 = *(const f16x8*)(smem +      0u + (unsigned)kk*1024u + lbase);
        f16x8 b1 = *(const f16x8*)(smem + 20480u + (unsigned)kk*1024u + lbase);
        f16x8 b2 = *(const f16x8*)(smem + 40960u + (unsigned)kk*1024u + lbase);
        acc[0][0] = MFMA16(ca0, b0, acc[0][0]);
        acc[1][0] = MFMA16(ca1, b0, acc[1][0]);
        acc[0][1] = MFMA16(ca0, b1, acc[0][1]);
        acc[1][1] = MFMA16(ca1, b1, acc[1][1]);
        acc[0][2] = MFMA16(ca0, b2, acc[0][2]);
        acc[1][2] = MFMA16(ca1, b2, acc[1][2]);
        if (kk+1 < KK_IH){ ca0 = na0; ca1 = na1; }
    }

    __syncthreads();
    {
        const int rb = (l >> 4)*4;
        const int jc = l & 15;
        #pragma unroll
        for (int mt=0; mt<2; ++mt){
            #pragma unroll
            for (int r=0; r<4; ++r){
                int ml = (wv*2 + mt)*16 + rb + r;
                *(f16*)(smem + ((0*256 + ml)*16 + jc)*2) = (f16)acc[mt][0][r];
                *(f16*)(smem + ((1*256 + ml)*16 + jc)*2) = (f16)acc[mt][1][r];
                *(f16*)(smem + ((2*256 + ml)*16 + jc)*2) = (f16)acc[mt][2][r];
            }
        }
    }
    __syncthreads();
    for (int u = tid; u < 1536; u += 512){
        int g  = u / 512;
        int rem = u - g*512;
        int ml = rem >> 1, half = rem & 1;
        size_t dst = ((size_t)(nt0+g)*3072 + (size_t)blockIdx.x*256 + ml)*16 + half*8;
        *(float4*)(&gi2[dst]) = *(const float4*)(smem + (size_t)u*16);
    }
}

// ---- recurrence GEMM (R13 grid/body, f16-only): 250 blocks (50 jtg x 5 ks) ----
__global__ __launch_bounds__(512) void k_gru_mfma(
    const f16* __restrict__ hhi,
    const f16* __restrict__ whi,
    float* __restrict__ part)
{
    __shared__ char smem[138240];   // 9 nt x 15 kk x 1KB (aliased as red after barrier)
    const int tid = threadIdx.x;
    const int wv = tid >> 6;        // 0..7
    const int l  = tid & 63;
    const int m  = wv & 3;          // m-tile (16 batch rows)
    const int kh = wv >> 2;         // k-half of 15 kk
    const int jtg = blockIdx.x;     // 0..49
    const int ks  = blockIdx.y;     // 0..4

    for (int off = tid*16; off < 138240; off += 8192){
        int ntl = off / 15360, rem = off - ntl*15360;
        int g = ntl/3, jtl = ntl - g*3;
        size_t nt = (size_t)(g*JT + jtg*3 + jtl);
        const char* src = (const char*)whi + (nt*KK_HH + (size_t)ks*KKB)*1024 + rem;
        *(float4*)(smem + off) = *(const float4*)src;
    }
    __syncthreads();

    const int kb   = kh ? 8 : 0;
    const int kcnt = kh ? 7 : 8;
    const int kk0  = ks*KKB + kb;

    const f16x8* pah = (const f16x8*)(hhi + ((size_t)(m*KK_HH + kk0)*64 + l)*8);

    f32x4 z4 = {0.f,0.f,0.f,0.f};
    f32x4 ah[9] = {z4,z4,z4,z4,z4,z4,z4,z4,z4};

    f16x8 cah = pah[0];
    for (int kk=0; kk<kcnt; ++kk){
        f16x8 nah;
        if (kk+1 < kcnt) nah = pah[(size_t)(kk+1)*64];
        const unsigned khh = (unsigned)(kb+kk)*1024u + (unsigned)l*16u;
        #pragma unroll
        for (int n=0; n<9; ++n){
            f16x8 bh = *(const f16x8*)(smem + (unsigned)n*15360u + khh);
            ah[n] = MFMA16(cah, bh, ah[n]);
        }
        if (kk+1 < kcnt) cah = nah;
    }

    __syncthreads();    // all LDS B-reads complete; safe to alias red over stage
    f32x4* red = (f32x4*)smem;
    if (kh == 1){
        #pragma unroll
        for (int n=0; n<9; ++n) red[(m*9+n)*64 + l] = ah[n];
    }
    __syncthreads();
    if (kh == 0){
        #pragma unroll
        for (int n=0; n<9; ++n){
            f32x4 v = ah[n] + red[(m*9+n)*64 + l];
            const int g = n/3, jtl = n - g*3;
            const size_t slot = (size_t)(ks*JT + jtg*3 + jtl);
            ((f32x4*)part)[((slot*3 + g)*4 + m)*64 + l] = v;
        }
    }
}

// ---- combine: sums 5 K-slices; h stored as single f16 frag pack ----
__global__ __launch_bounds__(256) void k_combine(
    int t, const float* __restrict__ part, const f16* __restrict__ gi2,
    const f16* __restrict__ chhi,
    f16* __restrict__ nhhi,
    const float* __restrict__ bhh, const int* __restrict__ lens,
    float* __restrict__ out)
{
    const int u  = blockIdx.x*256 + threadIdx.x;
    const int l  = u & 63;
    const int gm = u >> 6;
    const int jt = gm >> 2, m = gm & 3;
    const int jc = l & 15;
    const int j  = jt*16 + jc;
    const int b0 = m*16 + (l >> 4)*4;

    const f32x4* p4 = (const f32x4*)part;
    f32x4 sr = {0.f,0.f,0.f,0.f}, sz = sr, sn = sr;
    #pragma unroll
    for (int ks=0; ks<KS; ++ks){
        const size_t slot = (size_t)(ks*JT + jt);
        sr += p4[((slot*3 + 0)*4 + m)*64 + l];
        sz += p4[((slot*3 + 1)*4 + m)*64 + l];
        sn += p4[((slot*3 + 2)*4 + m)*64 + l];
    }
    const float br = bhh[j], bz = bhh[Hh + j], bn = bhh[2*Hh + j];
    const size_t fbase = ((size_t)(m*KK_HH + (jt >> 1))*64
                       + (size_t)(((jt & 1)*2 + (jc >> 3)) << 4) + (size_t)(l >> 4)*4)*8
                       + (size_t)(l & 7);
    #pragma unroll
    for (int r=0; r<4; ++r){
        const int b = b0 + r;
        const size_t row = (size_t)b*Tt + t;   // gi2 row order: m = b*Tt + t
        float gir = (float)gi2[((size_t)(0*JT + jt)*3072 + row)*16 + jc];
        float giz = (float)gi2[((size_t)(1*JT + jt)*3072 + row)*16 + jc];
        float gin = (float)gi2[((size_t)(2*JT + jt)*3072 + row)*16 + jc];
        float rg = sigf(gir + sr[r] + br);
        float zg = sigf(giz + sz[r] + bz);
        float ng = tanhf(gin + rg*(sn[r] + bn));
        const size_t fo = fbase + (size_t)r*8;
        float hp = (float)chhi[fo];
        float hn = (1.0f - zg)*ng + zg*hp;
        nhhi[fo] = (f16)hn;
        if (lens[b] - 1 == t) out[(size_t)b*Hh + j] = hn;
    }
}

// ---- fallback (small ws): plain fp32 ----
__global__ __launch_bounds__(256) void k_fb_step(
    int t, const float* __restrict__ hcur, float* __restrict__ hnext,
    const int* __restrict__ tokens, const int* __restrict__ lens,
    const float* __restrict__ emb, const float* __restrict__ wih,
    const float* __restrict__ whh, const float* __restrict__ bhh,
    float* __restrict__ out)
{
    __shared__ float sbuf[64][17];
    __shared__ int stok[64];
    const int tid = threadIdx.x;
    const int jl = tid & 7, rl = tid >> 3;
    const int j = blockIdx.x*8 + jl;
    if (tid < 64) stok[tid] = tokens[tid*Tt + t];

    float accr[2]={0.f,0.f}, accz[2]={0.f,0.f}, accnh[2]={0.f,0.f}, accni[2]={0.f,0.f};

    for (int k0=0; k0<Hh; k0+=16){
        __syncthreads();
        for (int e=tid; e<1024; e+=256)
            sbuf[e>>4][e&15] = hcur[(size_t)(e>>4)*Hh + k0 + (e&15)];
        __syncthreads();
        for (int kk=0; kk<16; ++kk){
            int k = k0 + kk;
            float wr = whh[(size_t)j*Hh + k];
            float wz = whh[(size_t)(Hh + j)*Hh + k];
            float wn = whh[(size_t)(2*Hh + j)*Hh + k];
            #pragma unroll
            for (int rr=0; rr<2; ++rr){
                float hv = sbuf[rl*2 + rr][kk];
                accr[rr] += wr*hv; accz[rr] += wz*hv; accnh[rr] += wn*hv;
            }
        }
    }
    for (int k0=0; k0<Ee; k0+=16){
        int lim = (Ee - k0 < 16) ? (Ee - k0) : 16;
        __syncthreads();
        for (int e=tid; e<1024; e+=256){
            int rr = e>>4, kkk = e&15;
            sbuf[rr][kkk] = (kkk < lim) ? emb[(size_t)stok[rr]*Ee + k0 + kkk] : 0.0f;
        }
        __syncthreads();
        for (int kk=0; kk<lim; ++kk){
            int k = k0 + kk;
            float wr = wih[(size_t)j*Ee + k];
            float wz = wih[(size_t)(Hh + j)*Ee + k];
            float wn = wih[(size_t)(2*Hh + j)*Ee + k];
            #pragma unroll
            for (int rr=0; rr<2; ++rr){
                float hv = sbuf[rl*2 + rr][kk];
                accr[rr] += wr*hv; accz[rr] += wz*hv; accni[rr] += wn*hv;
            }
        }
    }
    const float br = bhh[j], bz = bhh[Hh + j], bn = bhh[2*Hh + j];
    #pragma unroll
    for (int rr=0; rr<2; ++rr){
        int b = rl*2 + rr;
        float rg = sigf(accr[rr] + br);
        float zg = sigf(accz[rr] + bz);
        float ng = tanhf(accni[rr] + rg*(accnh[rr] + bn));
        float hp = hcur[(size_t)b*Hh + j];
        float hn = (1.0f - zg)*ng + zg*hp;
        hnext[(size_t)b*Hh + j] = hn;
        if (lens[b] - 1 == t) out[(size_t)b*Hh + j] = hn;
    }
}

static inline size_t alignup(size_t v){ return (v + 255) & ~(size_t)255; }

extern "C" void kernel_launch(void* const* d_in, const int* in_sizes, int n_in,
                              void* d_out, int out_size, void* d_ws, size_t ws_size,
                              hipStream_t stream)
{
    const int*   tokens = (const int*)d_in[0];
    const int*   lens   = (const int*)d_in[1];
    const float* emb    = (const float*)d_in[2];
    const float* wih    = (const float*)d_in[3];
    const float* whh    = (const float*)d_in[4];
    const float* bhh    = (const float*)d_in[5];
    float* out = (float*)d_out;

    char* ws = (char*)d_ws;
    size_t o = 0;
    const size_t o_whi  = o; o = alignup(o + WHH_ELEMS*2);
    const size_t o_wih  = o; o = alignup(o + WIH_ELEMS*2);  // reused as `part` after gi
    const size_t o_x    = o; o = alignup(o + X_ELEMS*2);
    const size_t o_gi   = o; o = alignup(o + GI_ELEMS*2);
    const size_t hbytes = HB*2;                              // hi pack only
    const size_t o_hbuf = o; o = alignup(o + 2*hbytes);
    const size_t need = o;   // ~94 MB

    if (ws_size >= need) {
        f16* whip = (f16*)(ws + o_whi);
        f16* wihp = (f16*)(ws + o_wih);
        float* part = (float*)(ws + o_wih);   // overlays wihp (dead after gi GEMM)
        f16* xp   = (f16*)(ws + o_x);
        f16* gip  = (f16*)(ws + o_gi);
        char* hb = ws + o_hbuf;
        f16* hhi[2] = { (f16*)hb, (f16*)(hb + hbytes) };

        hipMemsetAsync(hb, 0, 2*hbytes, stream);
        k_pack_whh<<<dim3((unsigned)((WHH_ELEMS+255)/256)), dim3(256), 0, stream>>>(whh, whip);
        k_pack_wih<<<dim3((unsigned)((WIH_ELEMS+255)/256)), dim3(256), 0, stream>>>(wih, wihp);
        k_gather_x<<<dim3((unsigned)((X_ELEMS+255)/256)),  dim3(256), 0, stream>>>(tokens, emb, xp);
        k_gi_gemm<<<dim3(12,150), dim3(512), 0, stream>>>(xp, wihp, gip);
        for (int t=0; t<Tt; ++t){
            int c = t & 1, n = c ^ 1;
            k_gru_mfma<<<dim3(JG, KS), dim3(512), 0, stream>>>(hhi[c], whip, part);
            k_combine<<<dim3(150), dim3(256), 0, stream>>>(t, part, gip,
                hhi[c], hhi[n], bhh, lens, out);
        }
    } else {
        float* h32 = (float*)ws;
        float* hbuf[2] = { h32, h32 + HB };
        hipMemsetAsync(ws, 0, 2*HB*4, stream);
        for (int t=0; t<Tt; ++t){
            int c = t & 1, n = c ^ 1;
            k_fb_step<<<dim3(300), dim3(256), 0, stream>>>(t, hbuf[c], hbuf[n],
                tokens, lens, emb, wih, whh, bhh, out);
        }
    }
}